// Round 8
// baseline (80.753 us; speedup 1.0000x reference)
//
#include <hip/hip_runtime.h>
#include <math.h>

// Layout R8 (= R7 maps, validated): ONE batch element per wave64.
// Amp p (8 bits): lane = bits 7..2 (6 lane bits, wires 0..5), pack axis =
// bit1 (wire 6), q = bit0 (wire 7).  State CR[2], CI[2] (v2f, .x=bit1=0).
// Packed math via EXPLICIT asm v_pk_* (r6-verified, incl. op_sel swap).
// Bit5 shuffle masks (32,48,40,60,34) use ds_bpermute with PRE-COMPUTED
// address registers (1 instr per shuffle); masks {1,2,3,7,8,15} use DPP;
// other <32 masks use ds_swizzle.
//
// Lane maps (r7, ref-verified): wire w -> lane bit k=5-w.
//  C1 U:(32,32)(16,16)(8,8)(4,4)(2,2)(1,1)      (5,6)ctrl 63  (7,0)V 48
//  C2 U:(32,48)(48,24)(56,12)(60,6)(62,3)(63,1) ctrl 21  V 40
//  C3 U:(32,40)(16,20)(40,10)(20,5)(42,2)(21,1) ctrl 51  V 60
//  C4 U:(32,60)(48,30)(24,15)(12,7)(38,3)(51,1) ctrl 17  V 34
//  QCNN: w0(32,34) w1(16,17) w2(8,8) w3(4,4) w4(34,2) w5(17,1)

typedef float v2f __attribute__((ext_vector_type(2)));

__device__ __forceinline__ v2f pkmul(v2f a, v2f b) {
  v2f d; asm("v_pk_mul_f32 %0, %1, %2" : "=v"(d) : "v"(a), "v"(b)); return d;
}
__device__ __forceinline__ v2f pkfma(v2f a, v2f b, v2f c) {
  v2f d; asm("v_pk_fma_f32 %0, %1, %2, %3" : "=v"(d) : "v"(a), "v"(b), "v"(c)); return d;
}
// src1 halves swapped: d.x = a.x*b.y + c.x ; d.y = a.y*b.x + c.y  (r6-verified)
__device__ __forceinline__ v2f pkfma_sw1(v2f a, v2f b, v2f c) {
  v2f d; asm("v_pk_fma_f32 %0, %1, %2, %3 op_sel:[0,1,0] op_sel_hi:[1,0,1]"
             : "=v"(d) : "v"(a), "v"(b), "v"(c)); return d;
}
__device__ __forceinline__ v2f dup(float x) { return (v2f){x, x}; }

template <int M>
__device__ __forceinline__ float shxm(float v) {
  static_assert(M < 32, "use shb for bit5 masks");
  if constexpr (M == 1 || M == 2 || M == 3 || M == 7 || M == 8 || M == 15) {
    constexpr int ctrl = (M == 1) ? 0xB1 : (M == 2) ? 0x4E : (M == 3) ? 0x1B
                         : (M == 7) ? 0x141 : (M == 8) ? 0x128 : 0x140;
    return __int_as_float(__builtin_amdgcn_update_dpp(
        0, __float_as_int(v), ctrl, 0xF, 0xF, true));
  } else {
    return __int_as_float(__builtin_amdgcn_ds_swizzle(
        __float_as_int(v), (M << 10) | 0x1F));
  }
}
__device__ __forceinline__ float shb(float v, int addr) {
  return __int_as_float(__builtin_amdgcn_ds_bpermute(addr, __float_as_int(v)));
}
template <int M>
__device__ __forceinline__ v2f shf2(v2f a, int addr) {
  if constexpr (M >= 32) {
    return (v2f){shb(a.x, addr), shb(a.y, addr)};
  } else {
    return (v2f){shxm<M>(a.x), shxm<M>(a.y)};
  }
}

struct G1 { float r00, i00, r01, i01, r10, i10, r11, i11; };

// element-invariant hoisted U coefficient vectors
struct UC {
  v2f Ar, Bi, BiN;          // dup(uAr), dup(uBi), dup(-uBi)
  v2f Aiv, AivN, Brv;       // {-uAip,uAip}, {uAip,-uAip}, {-uBrp,uBrp}
  v2f Aip2, AipN2, Brp2, BrpN2;  // dup(+-uAip), dup(+-uBrp)
  float uAip, uBrp;
};

// U = RZ@RY on a lane bit.
template <int RL, int VL>
__device__ __forceinline__ void u_lane(v2f (&CR)[2], v2f (&CI)[2], int l,
                                       const UC& u, int addr) {
  const bool hi = (__popc(l & RL) & 1) != 0;
  const float ai = hi ? u.uAip : -u.uAip;
  const float br = hi ? u.uBrp : -u.uBrp;
  const v2f cAi = dup(ai), cAiN = dup(-ai), cBr = dup(br);
  v2f PR[2], PI[2];
#pragma unroll
  for (int q = 0; q < 2; ++q) {
    PR[q] = shf2<VL>(CR[q], addr); PI[q] = shf2<VL>(CI[q], addr);
  }
#pragma unroll
  for (int q = 0; q < 2; ++q) {
    v2f NR = pkfma(u.BiN, PI[q], pkfma(cBr, PR[q], pkfma(cAiN, CI[q], pkmul(u.Ar, CR[q]))));
    v2f NI = pkfma(u.Bi, PR[q], pkfma(cBr, PI[q], pkfma(cAi, CR[q], pkmul(u.Ar, CI[q]))));
    CR[q] = NR; CI[q] = NI;
  }
}

// U on the pack axis (wire 6): op_sel-swapped src for partner terms.
__device__ __forceinline__ void u_pack(v2f (&CR)[2], v2f (&CI)[2], const UC& u) {
#pragma unroll
  for (int q = 0; q < 2; ++q) {
    const v2f XR = CR[q], XI = CI[q];
    CR[q] = pkfma_sw1(u.BiN, XI, pkfma_sw1(u.Brv, XR, pkfma(u.AivN, XI, pkmul(u.Ar, XR))));
    CI[q] = pkfma_sw1(u.Bi, XR, pkfma_sw1(u.Brv, XI, pkfma(u.Aiv, XR, pkmul(u.Ar, XI))));
  }
}

// U on bit0 (q pair): coefficients from hoisted vectors.
__device__ __forceinline__ void u_bit0(v2f (&CR)[2], v2f (&CI)[2], const UC& u) {
  const v2f LR = CR[0], LI = CI[0], HR = CR[1], HI = CI[1];
  // g00=(uAr,-uAip) g01=(-uBrp,uBi) g10=(uBrp,uBi) g11=(uAr,uAip)
  CR[0] = pkfma(u.BiN, HI, pkfma(u.BrpN2, HR, pkfma(u.Aip2, LI, pkmul(u.Ar, LR))));
  CI[0] = pkfma(u.Bi, HR, pkfma(u.BrpN2, HI, pkfma(u.AipN2, LR, pkmul(u.Ar, LI))));
  CR[1] = pkfma(u.BiN, HI, pkfma(u.Ar, HR, pkfma(u.BiN, LI, pkmul(u.Brp2, LR))));
  CI[1] = pkfma(u.Bi, HR, pkfma(u.Ar, HI, pkfma(u.Bi, LR, pkmul(u.Brp2, LI))));
  // note: CR[1] term -g11i*HI = -uAip*HI ... fix below (see wrapper)
}

// generic 2x2 complex gate on bit0, scalar coefficients (QCNN, few calls).
__device__ __forceinline__ void g_pair(v2f (&CR)[2], v2f (&CI)[2], float g00r,
                                       float g00i, float g01r, float g01i,
                                       float g10r, float g10i, float g11r,
                                       float g11i) {
  const v2f LR = CR[0], LI = CI[0], HR = CR[1], HI = CI[1];
  const v2f a00r = dup(g00r), a00i = dup(g00i), n00i = dup(-g00i);
  const v2f a01r = dup(g01r), a01i = dup(g01i), n01i = dup(-g01i);
  const v2f a10r = dup(g10r), a10i = dup(g10i), n10i = dup(-g10i);
  const v2f a11r = dup(g11r), a11i = dup(g11i), n11i = dup(-g11i);
  CR[0] = pkfma(n01i, HI, pkfma(a01r, HR, pkfma(n00i, LI, pkmul(a00r, LR))));
  CI[0] = pkfma(a01i, HR, pkfma(a01r, HI, pkfma(a00i, LR, pkmul(a00r, LI))));
  CR[1] = pkfma(n11i, HI, pkfma(a11r, HR, pkfma(n10i, LI, pkmul(a10r, LR))));
  CI[1] = pkfma(a11i, HR, pkfma(a11r, HI, pkfma(a10i, LR, pkmul(a10r, LI))));
}

// ring CNOT (5,6): lane-parity ctrl, conditional pack-half swap.
template <int RL>
__device__ __forceinline__ void cnot_l_pack(v2f (&CR)[2], v2f (&CI)[2], int l) {
  const bool c = (__popc(l & RL) & 1) != 0;
#pragma unroll
  for (int q = 0; q < 2; ++q) {
    const v2f r = CR[q], i = CI[q];
    CR[q] = (v2f){c ? r.y : r.x, c ? r.x : r.y};
    CI[q] = (v2f){c ? i.y : i.x, c ? i.x : i.y};
  }
}

// ring CNOT (6,7): swap hi halves of q0/q1.
__device__ __forceinline__ void cnot_pack_bit0(v2f (&CR)[2], v2f (&CI)[2]) {
  float t;
  t = CR[0].y; CR[0].y = CR[1].y; CR[1].y = t;
  t = CI[0].y; CI[0].y = CI[1].y; CI[1].y = t;
}

// ring CNOT (7,0): q=1 ctrl -> bpermute CR[1]/CI[1] (all V masks have bit5).
__device__ __forceinline__ void cnot_bit0_lane(v2f (&CR)[2], v2f (&CI)[2],
                                               int addr) {
  CR[1] = (v2f){shb(CR[1].x, addr), shb(CR[1].y, addr)};
  CI[1] = (v2f){shb(CI[1].x, addr), shb(CI[1].y, addr)};
}

// CRX lane-ctrl -> lane-target.
template <int RL, int VL>
__device__ __forceinline__ void crx_ll(v2f (&CR)[2], v2f (&CI)[2], int l,
                                       float co, float si) {
  const bool c = (__popc(l & RL) & 1) != 0;
  const float cf = c ? co : 1.f, sf = c ? si : 0.f;
  const v2f cc = dup(cf), ss = dup(sf), ssN = dup(-sf);
  v2f PR[2], PI[2];
#pragma unroll
  for (int q = 0; q < 2; ++q) {
    PR[q] = shf2<VL>(CR[q], 0); PI[q] = shf2<VL>(CI[q], 0);
  }
#pragma unroll
  for (int q = 0; q < 2; ++q) {
    CR[q] = pkfma(ss, PI[q], pkmul(cc, CR[q]));
    CI[q] = pkfma(ssN, PR[q], pkmul(cc, CI[q]));
  }
}

// CRX lane-ctrl -> pack-axis target (5,6): op_sel-swapped partner.
template <int RL>
__device__ __forceinline__ void crx_l_pack(v2f (&CR)[2], v2f (&CI)[2], int l,
                                           float co, float si) {
  const bool c = (__popc(l & RL) & 1) != 0;
  const float cf = c ? co : 1.f, sf = c ? si : 0.f;
  const v2f cc = dup(cf), ss = dup(sf), ssN = dup(-sf);
#pragma unroll
  for (int q = 0; q < 2; ++q) {
    v2f NR = pkfma_sw1(ss, CI[q], pkmul(cc, CR[q]));
    v2f NI = pkfma_sw1(ssN, CR[q], pkmul(cc, CI[q]));
    CR[q] = NR; CI[q] = NI;
  }
}

// CRX target bit0; cc/ss/ssN vectors (supports pack-ctrl (1,co)/(0,si)).
__device__ __forceinline__ void crx_pair(v2f (&CR)[2], v2f (&CI)[2], v2f cc,
                                         v2f ss, v2f ssN) {
  const v2f LR = CR[0], LI = CI[0], HR = CR[1], HI = CI[1];
  CR[0] = pkfma(ss, HI, pkmul(cc, LR));
  CI[0] = pkfma(ssN, HR, pkmul(cc, LI));
  CR[1] = pkfma(ss, LI, pkmul(cc, HR));
  CI[1] = pkfma(ssN, LR, pkmul(cc, HI));
}

// U3 on a lane bit.
template <int RL, int VL>
__device__ __forceinline__ void u3_lane(v2f (&CR)[2], v2f (&CI)[2], int l,
                                        const G1& g) {
  const bool hi = (__popc(l & RL) & 1) != 0;
  const float Ar = hi ? g.r11 : g.r00, Ai = hi ? g.i11 : g.i00;
  const float Br = hi ? g.r10 : g.r01, Bi = hi ? g.i10 : g.i01;
  const v2f cAr = dup(Ar), cAi = dup(Ai), cAiN = dup(-Ai);
  const v2f cBr = dup(Br), cBi = dup(Bi), cBiN = dup(-Bi);
  v2f PR[2], PI[2];
#pragma unroll
  for (int q = 0; q < 2; ++q) {
    PR[q] = shf2<VL>(CR[q], 0); PI[q] = shf2<VL>(CI[q], 0);
  }
#pragma unroll
  for (int q = 0; q < 2; ++q) {
    v2f NR = pkfma(cBiN, PI[q], pkfma(cBr, PR[q], pkfma(cAiN, CI[q], pkmul(cAr, CR[q]))));
    v2f NI = pkfma(cBi, PR[q], pkfma(cBr, PI[q], pkfma(cAi, CR[q], pkmul(cAr, CI[q]))));
    CR[q] = NR; CI[q] = NI;
  }
}

__device__ __forceinline__ G1 load_g1(const float* __restrict__ cs, int k) {
  const float* p = cs + 22 + 8 * k;
  G1 g;
  g.r00 = p[0]; g.i00 = p[1]; g.r01 = p[2]; g.i01 = p[3];
  g.r10 = p[4]; g.i10 = p[5]; g.r11 = p[6]; g.i11 = p[7];
  return g;
}

__global__ void prep_kernel(const float* __restrict__ crx,
                            const float* __restrict__ u3p,
                            float* __restrict__ ws) {
  const int t = threadIdx.x;
  if (t < 11) {
    float s, c;
    sincosf(0.5f * crx[t], &s, &c);
    ws[2 * t] = c; ws[2 * t + 1] = s;
  } else if (t >= 16 && t < 23) {
    const int k = t - 16;
    float st, ct, sp, cp, sl, cl;
    sincosf(0.5f * u3p[3 * k], &st, &ct);
    sincosf(u3p[3 * k + 1], &sp, &cp);
    sincosf(u3p[3 * k + 2], &sl, &cl);
    float* o = ws + 22 + 8 * k;
    o[0] = ct;            o[1] = 0.f;
    o[2] = -cl * st;      o[3] = -sl * st;
    o[4] = cp * st;       o[5] = sp * st;
    o[6] = (cp * cl - sp * sl) * ct;
    o[7] = (sp * cl + cp * sl) * ct;
  }
}

__global__ __launch_bounds__(256, 8) void qcnn_kernel(
    const float* __restrict__ theta, const float* __restrict__ phi,
    const float* __restrict__ cs, float* __restrict__ out, int nbatch) {
  const int lane = threadIdx.x & 63;
  int b = blockIdx.x * 4 + (threadIdx.x >> 6);
  if (b >= nbatch) b = nbatch - 1;

  // precomputed bpermute addresses for bit5 xor-masks
  const int a32 = ((lane ^ 32) << 2);
  const int a48 = ((lane ^ 48) << 2);
  const int a40 = ((lane ^ 40) << 2);
  const int a60 = ((lane ^ 60) << 2);
  const int a34 = ((lane ^ 34) << 2);

  v2f CR[2], CI[2];
  CR[0] = (v2f){lane == 0 ? 1.f : 0.f, 0.f};
  CR[1] = dup(0.f); CI[0] = dup(0.f); CI[1] = dup(0.f);

  float sth, cth, sph, cph;
  __sincosf(0.5f * theta[b], &sth, &cth);
  __sincosf(0.5f * phi[b], &sph, &cph);
  const float uAr = cph * cth, uBi = sph * sth;
  const float uAip = sph * cth, uBrp = cph * sth;

  UC u;
  u.Ar = dup(uAr); u.Bi = dup(uBi); u.BiN = dup(-uBi);
  u.Aiv = (v2f){-uAip, uAip}; u.AivN = (v2f){uAip, -uAip};
  u.Brv = (v2f){-uBrp, uBrp};
  u.Aip2 = dup(uAip); u.AipN2 = dup(-uAip);
  u.Brp2 = dup(uBrp); u.BrpN2 = dup(-uBrp);
  u.uAip = uAip; u.uBrp = uBrp;

#define UL(RL, VL, A) u_lane<RL, VL>(CR, CI, lane, u, A)
#define UREST() do { u_pack(CR, CI, u); \
                     g_pair(CR, CI, uAr, -uAip, -uBrp, uBi, \
                            uBrp, uBi, uAr, uAip); } while (0)
#define RING(RLC, A) do { cnot_l_pack<RLC>(CR, CI, lane); \
                          cnot_pack_bit0(CR, CI); \
                          cnot_bit0_lane(CR, CI, A); } while (0)

  // cycle 1
  UL(32, 32, a32); UL(16, 16, 0); UL(8, 8, 0);   UL(4, 4, 0);
  UL(2, 2, 0);     UL(1, 1, 0);   UREST(); RING(63, a48);
  // cycle 2
  UL(32, 48, a48); UL(48, 24, 0); UL(56, 12, 0); UL(60, 6, 0);
  UL(62, 3, 0);    UL(63, 1, 0);  UREST(); RING(21, a40);
  // cycle 3
  UL(32, 40, a40); UL(16, 20, 0); UL(40, 10, 0); UL(20, 5, 0);
  UL(42, 2, 0);    UL(21, 1, 0);  UREST(); RING(51, a60);
  // cycle 4
  UL(32, 60, a60); UL(48, 30, 0); UL(24, 15, 0); UL(12, 7, 0);
  UL(38, 3, 0);    UL(51, 1, 0);  UREST(); RING(17, a34);
#undef RING
#undef UREST
#undef UL

  // ---- QCNN section (maps: w0(32,34) w1(16,17) w2(8,8) w3(4,4) w4(34,2)
  // w5(17,1); wire6 = pack axis, wire7 = bit0) ----
#define LD(k) const float co##k = cs[2 * k], si##k = cs[2 * k + 1]
  LD(0); crx_ll<32, 17>(CR, CI, lane, co0, si0);  // (0,1)
  LD(1); crx_ll<8, 4>(CR, CI, lane, co1, si1);    // (2,3)
  LD(2); crx_ll<34, 1>(CR, CI, lane, co2, si2);   // (4,5)
  LD(3); crx_pair(CR, CI, (v2f){1.f, co3}, (v2f){0.f, si3},
                  (v2f){0.f, -si3});              // (6,7)
  LD(4); crx_ll<16, 8>(CR, CI, lane, co4, si4);   // (1,2)
  LD(5); crx_ll<4, 2>(CR, CI, lane, co5, si5);    // (3,4)
  LD(6); crx_l_pack<17>(CR, CI, lane, co6, si6);  // (5,6)

  { G1 g = load_g1(cs, 0); u3_lane<16, 17>(CR, CI, lane, g); }  // wire 1
  { G1 g = load_g1(cs, 1); u3_lane<4, 4>(CR, CI, lane, g); }    // wire 3
  { G1 g = load_g1(cs, 2); u3_lane<17, 1>(CR, CI, lane, g); }   // wire 5
  { G1 g = load_g1(cs, 3);                                      // wire 7
    g_pair(CR, CI, g.r00, g.i00, g.r01, g.i01, g.r10, g.i10, g.r11, g.i11); }

  LD(7); crx_ll<16, 4>(CR, CI, lane, co7, si7);   // (1,3)
  LD(8);                                          // (5,7): lane ctrl 17
  {
    const bool c = (__popc(lane & 17) & 1) != 0;
    const float cf = c ? co8 : 1.f, sf = c ? si8 : 0.f;
    crx_pair(CR, CI, dup(cf), dup(sf), dup(-sf));
  }
  LD(9); crx_ll<4, 1>(CR, CI, lane, co9, si9);    // (3,5)

  { G1 g = load_g1(cs, 4); u3_lane<4, 4>(CR, CI, lane, g); }    // wire 3
  { G1 g = load_g1(cs, 5);                                      // wire 7
    g_pair(CR, CI, g.r00, g.i00, g.r01, g.i01, g.r10, g.i10, g.r11, g.i11); }

  LD(10);                                         // (3,7): lane ctrl 4
  {
    const bool c = (__popc(lane & 4) & 1) != 0;
    const float cf = c ? co10 : 1.f, sf = c ? si10 : 0.f;
    crx_pair(CR, CI, dup(cf), dup(sf), dup(-sf));
  }

  { G1 g = load_g1(cs, 6);                                      // wire 7
    g_pair(CR, CI, g.r00, g.i00, g.r01, g.i01, g.r10, g.i10, g.r11, g.i11); }
#undef LD

  // <Z_wire7>: sign = q bit; reduce over 64 lanes.
  const v2f T = pkfma(CR[0], CR[0], pkmul(CI[0], CI[0]))
              - pkfma(CR[1], CR[1], pkmul(CI[1], CI[1]));
  float v = T.x + T.y;
  v += shxm<1>(v); v += shxm<2>(v); v += shxm<4>(v);
  v += shxm<8>(v); v += shxm<16>(v); v += shb(v, a32);
  if (lane == 0) out[b] = fmaxf(v, 0.f);
}

extern "C" void kernel_launch(void* const* d_in, const int* in_sizes, int n_in,
                              void* d_out, int out_size, void* d_ws, size_t ws_size,
                              hipStream_t stream) {
  const float* theta = (const float*)d_in[0];
  const float* phi = (const float*)d_in[1];
  const float* crx = (const float*)d_in[2];
  const float* u3p = (const float*)d_in[3];
  float* out = (float*)d_out;
  float* ws = (float*)d_ws;
  const int nb = in_sizes[0];

  prep_kernel<<<1, 64, 0, stream>>>(crx, u3p, ws);

  const int elems_per_block = 4;  // 4 waves * 1 element
  dim3 block(256);
  dim3 grid((nb + elems_per_block - 1) / elems_per_block);
  qcnn_kernel<<<grid, block, 0, stream>>>(theta, phi, ws, out, nb);
}

// Round 9
// 75.270 us; speedup vs baseline: 1.0728x; 1.0728x over previous
//
#include <hip/hip_runtime.h>
#include <math.h>

// Base = round-6 kernel (best measured: 78.18 us total), layout unchanged:
// 8 complex amps/lane, 2 batch elements/wave64 (one per 32-lane half).
// Amp p = l<<3 | r, l = lane&31 (5 lane bits, wires 0..4), r = reg (3 bits:
// bit2=wire5=pack axis, bit1=wire6, bit0=wire7).  Regs packed as float2
// along reg bit2.  asm v_pk_* math, DPP/ds_swizzle shuffles, prep kernel
// for batch-invariant coefficients.
//
// Round 9 changes (slot cuts via algebra, structure untouched):
//  1. Cycle-1 closed form: U(x8)|0..0> is a PRODUCT state:
//     amp(x) = g0^(8-k) g1^k, k = popc(x), g0 = e^{-i phi/2} c, g1 = e^{+i
//     phi/2} s.  Replaces 5 u_lane + UREGS (~220 slots, 20 shuffles) with
//     ~85 pure-VALU slots.  Ring physical parts unchanged.
//  2. Folded measurement: tail U3(5);CRX(3,7);U3(6);<Z7> == s^H M_c s with
//     M_c = U3_5^H RX_c^H U3_6^H Z U3_6 RX_c U3_5, c = parity(lane&2) --
//     two 2x2 Hermitian forms prep-computed into ws[80..87].
//
// Lane-bit lazy GF(2) CNOT relabeling (validated r4/r5/r6):
//  C2 U:(16,24)(24,12)(28,6)(30,3)(31,1) lr-ctrl 21  rl-V 20
//  C3 U:(16,20)(8,10)(20,5)(10,2)(21,1)  lr-ctrl 19  rl-V 30
//  C4 U:(16,30)(24,15)(12,7)(6,3)(19,1)  lr-ctrl 17  rl-V 17
//  QCNN: w0(16,17) w1(8,8) w2(4,4) w3(2,2) w4(17,1); reg wires 5,6,7=bits 2,1,0.

typedef float v2f __attribute__((ext_vector_type(2)));

__device__ __forceinline__ v2f pkmul(v2f a, v2f b) {
  v2f d; asm("v_pk_mul_f32 %0, %1, %2" : "=v"(d) : "v"(a), "v"(b)); return d;
}
__device__ __forceinline__ v2f pkfma(v2f a, v2f b, v2f c) {
  v2f d; asm("v_pk_fma_f32 %0, %1, %2, %3" : "=v"(d) : "v"(a), "v"(b), "v"(c)); return d;
}
__device__ __forceinline__ v2f pkmul_lo1(v2f a, v2f b) {
  v2f d; asm("v_pk_mul_f32 %0, %1, %2 op_sel:[0,0] op_sel_hi:[1,0]"
             : "=v"(d) : "v"(a), "v"(b)); return d;
}
__device__ __forceinline__ v2f pkfma_lo1(v2f a, v2f b, v2f c) {
  v2f d; asm("v_pk_fma_f32 %0, %1, %2, %3 op_sel:[0,0,0] op_sel_hi:[1,0,1]"
             : "=v"(d) : "v"(a), "v"(b), "v"(c)); return d;
}
__device__ __forceinline__ v2f pkfma_hi1(v2f a, v2f b, v2f c) {
  v2f d; asm("v_pk_fma_f32 %0, %1, %2, %3 op_sel:[0,1,0] op_sel_hi:[1,1,1]"
             : "=v"(d) : "v"(a), "v"(b), "v"(c)); return d;
}
__device__ __forceinline__ v2f pkfma_sw1(v2f a, v2f b, v2f c) {
  v2f d; asm("v_pk_fma_f32 %0, %1, %2, %3 op_sel:[0,1,0] op_sel_hi:[1,0,1]"
             : "=v"(d) : "v"(a), "v"(b), "v"(c)); return d;
}
__device__ __forceinline__ v2f dup(float x) { return (v2f){x, x}; }

template <int M>
__device__ __forceinline__ float shxm(float v) {
  if constexpr (M == 1 || M == 2 || M == 3 || M == 7 || M == 8 || M == 15) {
    constexpr int ctrl = (M == 1) ? 0xB1 : (M == 2) ? 0x4E : (M == 3) ? 0x1B
                         : (M == 7) ? 0x141 : (M == 8) ? 0x128 : 0x140;
    return __int_as_float(__builtin_amdgcn_update_dpp(
        0, __float_as_int(v), ctrl, 0xF, 0xF, true));
  } else {
    return __int_as_float(__builtin_amdgcn_ds_swizzle(
        __float_as_int(v), (M << 10) | 0x1F));
  }
}
template <int M>
__device__ __forceinline__ v2f shf2(v2f a) {
  return (v2f){shxm<M>(a.x), shxm<M>(a.y)};
}

struct G1 { float r00, i00, r01, i01, r10, i10, r11, i11; };

// generic 2x2 complex gate on a reg pair (lo,hi) across two packs.
__device__ __forceinline__ void apply_pair(v2f& LR, v2f& LI, v2f& HR, v2f& HI,
                                           float g00r, float g00i, float g01r,
                                           float g01i, float g10r, float g10i,
                                           float g11r, float g11i) {
  const v2f a00r = dup(g00r), a00i = dup(g00i), n00i = dup(-g00i);
  const v2f a01r = dup(g01r), a01i = dup(g01i), n01i = dup(-g01i);
  const v2f a10r = dup(g10r), a10i = dup(g10i), n10i = dup(-g10i);
  const v2f a11r = dup(g11r), a11i = dup(g11i), n11i = dup(-g11i);
  v2f NLR = pkfma(n01i, HI, pkfma(a01r, HR, pkfma(n00i, LI, pkmul(a00r, LR))));
  v2f NLI = pkfma(a01i, HR, pkfma(a01r, HI, pkfma(a00i, LR, pkmul(a00r, LI))));
  v2f NHR = pkfma(n11i, HI, pkfma(a11r, HR, pkfma(n10i, LI, pkmul(a10r, LR))));
  v2f NHI = pkfma(a11i, HR, pkfma(a11r, HI, pkfma(a10i, LR, pkmul(a10r, LI))));
  LR = NLR; LI = NLI; HR = NHR; HI = NHI;
}

__device__ __forceinline__ void crx_pairv(v2f& LR, v2f& LI, v2f& HR, v2f& HI,
                                          v2f cCC, v2f cSS, v2f cSSN) {
  v2f NLR = pkfma(cSS, HI, pkmul(cCC, LR));
  v2f NLI = pkfma(cSSN, HR, pkmul(cCC, LI));
  v2f NHR = pkfma(cSS, LI, pkmul(cCC, HR));
  v2f NHI = pkfma(cSSN, LR, pkmul(cCC, HI));
  LR = NLR; LI = NLI; HR = NHR; HI = NHI;
}

// U = RZ@RY on a lane bit (fully packed).
template <int RL, int VL>
__device__ __forceinline__ void u_lane(v2f (&CR)[4], v2f (&CI)[4], int l,
                                       float uAr, float uBi, float uAip,
                                       float uBrp) {
  const bool hi = (__popc(l & RL) & 1) != 0;
  const float Ai = hi ? uAip : -uAip;
  const float Br = hi ? uBrp : -uBrp;
  const v2f cAr = dup(uAr), cAi = dup(Ai), cAiN = dup(-Ai);
  const v2f cBr = dup(Br), cBi = dup(uBi), cBiN = dup(-uBi);
  v2f PR[4], PI[4];
#pragma unroll
  for (int q = 0; q < 4; ++q) { PR[q] = shf2<VL>(CR[q]); PI[q] = shf2<VL>(CI[q]); }
#pragma unroll
  for (int q = 0; q < 4; ++q) {
    v2f NR = pkfma(cBiN, PI[q], pkfma(cBr, PR[q], pkfma(cAiN, CI[q], pkmul(cAr, CR[q]))));
    v2f NI = pkfma(cBi, PR[q], pkfma(cBr, PI[q], pkfma(cAi, CR[q], pkmul(cAr, CI[q]))));
    CR[q] = NR; CI[q] = NI;
  }
}

// generic 2x2 gate on the PACK axis via op_sel (8 pk per pack).
__device__ __forceinline__ void gate_pack(v2f (&CR)[4], v2f (&CI)[4],
                                          v2f cA, v2f cB, v2f cBn,
                                          v2f cC, v2f cD, v2f cDn) {
#pragma unroll
  for (int q = 0; q < 4; ++q) {
    v2f NR = pkfma_hi1(cDn, CI[q], pkfma_hi1(cC, CR[q],
             pkfma_lo1(cBn, CI[q], pkmul_lo1(cA, CR[q]))));
    v2f NI = pkfma_hi1(cD, CR[q], pkfma_hi1(cC, CI[q],
             pkfma_lo1(cB, CR[q], pkmul_lo1(cA, CI[q]))));
    CR[q] = NR; CI[q] = NI;
  }
}

__device__ __forceinline__ void u_reg4(v2f (&CR)[4], v2f (&CI)[4], float uAr,
                                       float uBi, float uAip, float uBrp) {
  gate_pack(CR, CI,
            (v2f){uAr, uBrp}, (v2f){-uAip, uBi}, (v2f){uAip, -uBi},
            (v2f){-uBrp, uAr}, (v2f){uBi, uAip}, (v2f){-uBi, -uAip});
}

__device__ __forceinline__ void u3_reg4(v2f (&CR)[4], v2f (&CI)[4], const G1& g) {
  gate_pack(CR, CI,
            (v2f){g.r00, g.r10}, (v2f){g.i00, g.i10}, (v2f){-g.i00, -g.i10},
            (v2f){g.r01, g.r11}, (v2f){g.i01, g.i11}, (v2f){-g.i01, -g.i11});
}

// ring CNOT (3,4)->(4,5): lane ctrl -> conditional .x/.y swap.
template <int RL>
__device__ __forceinline__ void cnot_lr4(v2f (&CR)[4], v2f (&CI)[4], int l) {
  const bool c = (__popc(l & RL) & 1) != 0;
#pragma unroll
  for (int q = 0; q < 4; ++q) {
    const float ax = CR[q].x, ay = CR[q].y;
    CR[q] = (v2f){c ? ay : ax, c ? ax : ay};
    const float bx = CI[q].x, by = CI[q].y;
    CI[q] = (v2f){c ? by : bx, c ? bx : by};
  }
}

__device__ __forceinline__ void cnot_swap42(v2f (&CR)[4], v2f (&CI)[4]) {
  float t;
  t = CR[0].y; CR[0].y = CR[2].y; CR[2].y = t;
  t = CR[1].y; CR[1].y = CR[3].y; CR[3].y = t;
  t = CI[0].y; CI[0].y = CI[2].y; CI[2].y = t;
  t = CI[1].y; CI[1].y = CI[3].y; CI[3].y = t;
}

__device__ __forceinline__ void cnot_swap21(v2f (&CR)[4], v2f (&CI)[4]) {
  v2f t;
  t = CR[2]; CR[2] = CR[3]; CR[3] = t;
  t = CI[2]; CI[2] = CI[3]; CI[3] = t;
}

template <int VL>
__device__ __forceinline__ void cnot_rl(v2f (&CR)[4], v2f (&CI)[4]) {
  CR[1] = shf2<VL>(CR[1]); CI[1] = shf2<VL>(CI[1]);
  CR[3] = shf2<VL>(CR[3]); CI[3] = shf2<VL>(CI[3]);
}

template <int RL, int VL>
__device__ __forceinline__ void crx_ll(v2f (&CR)[4], v2f (&CI)[4], int l,
                                       float co, float si) {
  const bool c = (__popc(l & RL) & 1) != 0;
  const float cc = c ? co : 1.f, ss = c ? si : 0.f;
  const v2f cCC = dup(cc), cSS = dup(ss), cSSN = dup(-ss);
  v2f PR[4], PI[4];
#pragma unroll
  for (int q = 0; q < 4; ++q) { PR[q] = shf2<VL>(CR[q]); PI[q] = shf2<VL>(CI[q]); }
#pragma unroll
  for (int q = 0; q < 4; ++q) {
    CR[q] = pkfma(cSS, PI[q], pkmul(cCC, CR[q]));
    CI[q] = pkfma(cSSN, PR[q], pkmul(cCC, CI[q]));
  }
}

template <int RL>
__device__ __forceinline__ void crx_lr4(v2f (&CR)[4], v2f (&CI)[4], int l,
                                        float co, float si) {
  const bool c = (__popc(l & RL) & 1) != 0;
  const float cc = c ? co : 1.f, ss = c ? si : 0.f;
  const v2f cc2 = dup(cc), ss2 = dup(ss), ssN2 = dup(-ss);
#pragma unroll
  for (int q = 0; q < 4; ++q) {
    v2f NR = pkfma_sw1(ss2, CI[q], pkmul(cc2, CR[q]));
    v2f NI = pkfma_sw1(ssN2, CR[q], pkmul(cc2, CI[q]));
    CR[q] = NR; CI[q] = NI;
  }
}

template <int RL, int VL>
__device__ __forceinline__ void u3_lane(v2f (&CR)[4], v2f (&CI)[4], int l,
                                        const G1& g) {
  const bool hi = (__popc(l & RL) & 1) != 0;
  const float Ar = hi ? g.r11 : g.r00, Aii = hi ? g.i11 : g.i00;
  const float Br = hi ? g.r10 : g.r01, Bi = hi ? g.i10 : g.i01;
  const v2f cAr = dup(Ar), cAi = dup(Aii), cAiN = dup(-Aii);
  const v2f cBr = dup(Br), cBi = dup(Bi), cBiN = dup(-Bi);
  v2f PR[4], PI[4];
#pragma unroll
  for (int q = 0; q < 4; ++q) { PR[q] = shf2<VL>(CR[q]); PI[q] = shf2<VL>(CI[q]); }
#pragma unroll
  for (int q = 0; q < 4; ++q) {
    v2f NR = pkfma(cBiN, PI[q], pkfma(cBr, PR[q], pkfma(cAiN, CI[q], pkmul(cAr, CR[q]))));
    v2f NI = pkfma(cBi, PR[q], pkfma(cBr, PI[q], pkfma(cAi, CR[q], pkmul(cAr, CI[q]))));
    CR[q] = NR; CI[q] = NI;
  }
}

__device__ __forceinline__ G1 load_g1(const float* __restrict__ cs, int k) {
  const float* p = cs + 22 + 8 * k;
  G1 g;
  g.r00 = p[0]; g.i00 = p[1]; g.r01 = p[2]; g.i01 = p[3];
  g.r10 = p[4]; g.i10 = p[5]; g.r11 = p[6]; g.i11 = p[7];
  return g;
}

// ---- prep: batch-invariant coefficients -> d_ws ----
// ws[0..21]: (co,si) crx[0..10]; ws[22+8k..]: G1 u3 gate k;
// ws[80..83]: M0 (m00, m11, 2Re m01, -2Im m01); ws[84..87]: M1.
struct Cx { float r, i; };
__device__ __forceinline__ Cx cmul(Cx a, Cx b) {
  return {a.r * b.r - a.i * b.i, a.r * b.i + a.i * b.r};
}
__device__ __forceinline__ Cx cconj(Cx a) { return {a.r, -a.i}; }
__device__ __forceinline__ Cx cadd(Cx a, Cx b) { return {a.r + b.r, a.i + b.i}; }
__device__ __forceinline__ Cx csub(Cx a, Cx b) { return {a.r - b.r, a.i - b.i}; }
__device__ __forceinline__ Cx cscale(float s, Cx a) { return {s * a.r, s * a.i}; }

// M = G^H N G for Hermitian N = [[n00, n01],[n01*, n11]] (n00,n11 real)
__device__ void congr(float n00, Cx n01, float n11, Cx G00, Cx G01, Cx G10,
                      Cx G11, float& m00, Cx& m01, float& m11) {
  Cx t0 = cadd(cscale(n00, G00), cmul(n01, G10));
  Cx t1 = cadd(cmul(cconj(n01), G00), cscale(n11, G10));
  Cx u0 = cadd(cscale(n00, G01), cmul(n01, G11));
  Cx u1 = cadd(cmul(cconj(n01), G01), cscale(n11, G11));
  m00 = cadd(cmul(cconj(G00), t0), cmul(cconj(G10), t1)).r;
  m01 = cadd(cmul(cconj(G00), u0), cmul(cconj(G10), u1));
  m11 = cadd(cmul(cconj(G01), u0), cmul(cconj(G11), u1)).r;
}

__device__ void build_u3(float t, float p, float l, Cx& G00, Cx& G01, Cx& G10,
                         Cx& G11) {
  float st, ct, sp, cp, sl, cl;
  sincosf(0.5f * t, &st, &ct);
  sincosf(p, &sp, &cp);
  sincosf(l, &sl, &cl);
  G00 = {ct, 0.f};
  G01 = {-cl * st, -sl * st};
  G10 = {cp * st, sp * st};
  G11 = {(cp * cl - sp * sl) * ct, (sp * cl + cp * sl) * ct};
}

__global__ void prep_kernel(const float* __restrict__ crx,
                            const float* __restrict__ u3p,
                            float* __restrict__ ws) {
  const int t = threadIdx.x;
  if (t < 11) {
    float s, c;
    sincosf(0.5f * crx[t], &s, &c);
    ws[2 * t] = c; ws[2 * t + 1] = s;
  } else if (t >= 16 && t < 23) {
    const int k = t - 16;
    float st, ct, sp, cp, sl, cl;
    sincosf(0.5f * u3p[3 * k], &st, &ct);
    sincosf(u3p[3 * k + 1], &sp, &cp);
    sincosf(u3p[3 * k + 2], &sl, &cl);
    float* o = ws + 22 + 8 * k;
    o[0] = ct;            o[1] = 0.f;
    o[2] = -cl * st;      o[3] = -sl * st;
    o[4] = cp * st;       o[5] = sp * st;
    o[6] = (cp * cl - sp * sl) * ct;
    o[7] = (sp * cl + cp * sl) * ct;
  } else if (t == 30) {
    // folded measurement matrices
    Cx A00, A01, A10, A11, C00, C01, C10, C11;
    build_u3(u3p[15], u3p[16], u3p[17], A00, A01, A10, A11);  // u3 gate 5
    build_u3(u3p[18], u3p[19], u3p[20], C00, C01, C10, C11);  // u3 gate 6
    // N = C^H Z C
    float n00 = (C00.r * C00.r + C00.i * C00.i) - (C10.r * C10.r + C10.i * C10.i);
    Cx n01 = csub(cmul(cconj(C00), C01), cmul(cconj(C10), C11));
    float n11 = (C01.r * C01.r + C01.i * C01.i) - (C11.r * C11.r + C11.i * C11.i);
    // M0 = A^H N A
    float m00, m11; Cx m01;
    congr(n00, n01, n11, A00, A01, A10, A11, m00, m01, m11);
    ws[80] = m00; ws[81] = m11; ws[82] = 2.f * m01.r; ws[83] = -2.f * m01.i;
    // M1 = A^H RX^H N RX A
    float co, si;
    sincosf(0.5f * crx[10], &si, &co);
    Cx R00 = {co, 0.f}, R01 = {0.f, -si}, R10 = {0.f, -si}, R11 = {co, 0.f};
    float p00, p11; Cx p01;
    congr(n00, n01, n11, R00, R01, R10, R11, p00, p01, p11);
    congr(p00, p01, p11, A00, A01, A10, A11, m00, m01, m11);
    ws[84] = m00; ws[85] = m11; ws[86] = 2.f * m01.r; ws[87] = -2.f * m01.i;
  }
}

__global__ __launch_bounds__(256, 4) void qcnn_kernel(
    const float* __restrict__ theta, const float* __restrict__ phi,
    const float* __restrict__ cs, float* __restrict__ out, int nbatch) {
  const int tid = blockIdx.x * blockDim.x + threadIdx.x;
  const int wave = tid >> 6;
  const int lane = threadIdx.x & 63;
  const int l = lane & 31;
  int b = wave * 2 + (lane >> 5);
  if (b >= nbatch) b = nbatch - 1;

  float sth, cth, sph, cph;
  __sincosf(0.5f * theta[b], &sth, &cth);
  __sincosf(0.5f * phi[b], &sph, &cph);
  const float uAr = cph * cth, uBi = sph * sth;
  const float uAip = sph * cth, uBrp = cph * sth;

  // ---- cycle-1 closed form: amp(x) = g0^(8-k) g1^k, k = popc(x) ----
  // g0 = U00 = (uAr, -uAip); g1 = U10 = (uBrp, uBi).
  const float g0r = uAr, g0i = -uAip, g1r = uBrp, g1i = uBi;
  float Zr = (l & 16) ? g1r : g0r, Zi = (l & 16) ? g1i : g0i;
#define MULBIT(m)                                                     \
  {                                                                   \
    const float Fr = (l & m) ? g1r : g0r, Fi = (l & m) ? g1i : g0i;   \
    const float nr = Zr * Fr - Zi * Fi, ni = Zr * Fi + Zi * Fr;       \
    Zr = nr; Zi = ni;                                                 \
  }
  MULBIT(8) MULBIT(4) MULBIT(2) MULBIT(1)
#undef MULBIT
  // h_j = g0^(3-j) g1^j for the 3 reg bits
  const float g00r = g0r * g0r - g0i * g0i, g00i = 2.f * g0r * g0i;
  const float g11r = g1r * g1r - g1i * g1i, g11i = 2.f * g1r * g1i;
  const float h0r = g00r * g0r - g00i * g0i, h0i = g00r * g0i + g00i * g0r;
  const float h1r = g00r * g1r - g00i * g1i, h1i = g00r * g1i + g00i * g1r;
  const float h2r = g11r * g0r - g11i * g0i, h2i = g11r * g0i + g11i * g0r;
  const float h3r = g11r * g1r - g11i * g1i, h3i = g11r * g1i + g11i * g1r;

  v2f CR[4], CI[4];
  {
    const v2f Zrv = dup(Zr), Ziv = dup(Zi), ZivN = dup(-Zi);
    const v2f Hr[4] = {{h0r, h1r}, {h1r, h2r}, {h1r, h2r}, {h2r, h3r}};
    const v2f Hi[4] = {{h0i, h1i}, {h1i, h2i}, {h1i, h2i}, {h2i, h3i}};
#pragma unroll
    for (int q = 0; q < 4; ++q) {
      CR[q] = pkfma(ZivN, Hi[q], pkmul(Zrv, Hr[q]));
      CI[q] = pkfma(Ziv, Hr[q], pkmul(Zrv, Hi[q]));
    }
  }

#define ULANE(RL, VL) u_lane<RL, VL>(CR, CI, l, uAr, uBi, uAip, uBrp)
#define UREGS() do { u_reg4(CR, CI, uAr, uBi, uAip, uBrp); \
                     apply_pair(CR[0], CI[0], CR[2], CI[2], uAr, -uAip, \
                                -uBrp, uBi, uBrp, uBi, uAr, uAip); \
                     apply_pair(CR[1], CI[1], CR[3], CI[3], uAr, -uAip, \
                                -uBrp, uBi, uBrp, uBi, uAr, uAip); \
                     apply_pair(CR[0], CI[0], CR[1], CI[1], uAr, -uAip, \
                                -uBrp, uBi, uBrp, uBi, uAr, uAip); \
                     apply_pair(CR[2], CI[2], CR[3], CI[3], uAr, -uAip, \
                                -uBrp, uBi, uBrp, uBi, uAr, uAip); } while (0)
#define RING(RL45, VL70) do { cnot_lr4<RL45>(CR, CI, l); \
                              cnot_swap42(CR, CI); cnot_swap21(CR, CI); \
                              cnot_rl<VL70>(CR, CI); } while (0)

  // cycle 1 ring (U part replaced by closed form above)
  RING(31, 24);
  // cycle 2
  ULANE(16, 24); ULANE(24, 12); ULANE(28, 6);  ULANE(30, 3); ULANE(31, 1);
  UREGS(); RING(21, 20);
  // cycle 3
  ULANE(16, 20); ULANE(8, 10);  ULANE(20, 5);  ULANE(10, 2); ULANE(21, 1);
  UREGS(); RING(19, 30);
  // cycle 4
  ULANE(16, 30); ULANE(24, 15); ULANE(12, 7);  ULANE(6, 3);  ULANE(19, 1);
  UREGS(); RING(17, 17);
#undef RING
#undef UREGS
#undef ULANE

  // ---- QCNN section ----
#define LD(k) const float co##k = cs[2 * k], si##k = cs[2 * k + 1]
  LD(0); crx_ll<16, 8>(CR, CI, l, co0, si0);   // (0,1)
  LD(1); crx_ll<4, 2>(CR, CI, l, co1, si1);    // (2,3)
  LD(2); crx_lr4<17>(CR, CI, l, co2, si2);     // (4,5) pack-target
  LD(3);                                       // (6,7): ctrl bit1, tgt bit0
  crx_pairv(CR[2], CI[2], CR[3], CI[3], dup(co3), dup(si3), dup(-si3));
  LD(4); crx_ll<8, 4>(CR, CI, l, co4, si4);    // (1,2)
  LD(5); crx_ll<2, 1>(CR, CI, l, co5, si5);    // (3,4)
  LD(6);                                       // (5,6): ctrl pack -> half coeffs
  {
    const v2f cCC = (v2f){1.f, co6}, cSS = (v2f){0.f, si6}, cSSN = (v2f){0.f, -si6};
    crx_pairv(CR[0], CI[0], CR[2], CI[2], cCC, cSS, cSSN);
    crx_pairv(CR[1], CI[1], CR[3], CI[3], cCC, cSS, cSSN);
  }

  { G1 g = load_g1(cs, 0); u3_lane<8, 8>(CR, CI, l, g); }  // wire 1
  { G1 g = load_g1(cs, 1); u3_lane<2, 2>(CR, CI, l, g); }  // wire 3
  { G1 g = load_g1(cs, 2); u3_reg4(CR, CI, g); }           // wire 5 pack
  { G1 g = load_g1(cs, 3);                                 // wire 7 (bit0)
    apply_pair(CR[0], CI[0], CR[1], CI[1], g.r00, g.i00, g.r01, g.i01,
               g.r10, g.i10, g.r11, g.i11);
    apply_pair(CR[2], CI[2], CR[3], CI[3], g.r00, g.i00, g.r01, g.i01,
               g.r10, g.i10, g.r11, g.i11); }

  LD(7); crx_ll<8, 2>(CR, CI, l, co7, si7);    // (1,3)
  LD(8);                                       // (5,7): ctrl pack, tgt bit0
  {
    const v2f cCC = (v2f){1.f, co8}, cSS = (v2f){0.f, si8}, cSSN = (v2f){0.f, -si8};
    crx_pairv(CR[0], CI[0], CR[1], CI[1], cCC, cSS, cSSN);
    crx_pairv(CR[2], CI[2], CR[3], CI[3], cCC, cSS, cSSN);
  }
  LD(9); crx_lr4<2>(CR, CI, l, co9, si9);      // (3,5) pack-target

  { G1 g = load_g1(cs, 4); u3_lane<2, 2>(CR, CI, l, g); }  // wire 3
#undef LD

  // ---- folded measurement: ev = s^H M_c s, c = parity(l&2) ----
  // (replaces u3#5, crx#10, u3#6 and the Z7 sum)
  {
    const bool cH = (l & 2) != 0;
    const float w00 = cH ? cs[84] : cs[80];
    const float w11 = cH ? cs[85] : cs[81];
    const float wa  = cH ? cs[86] : cs[82];
    const float wb  = cH ? cs[87] : cs[83];
    // bit0 pairs: (q0,q1) and (q2,q3), both .x and .y halves valid pairs
    v2f PL = pkfma(CI[0], CI[0], pkmul(CR[0], CR[0]));
    PL = PL + pkfma(CI[2], CI[2], pkmul(CR[2], CR[2]));
    v2f PH = pkfma(CI[1], CI[1], pkmul(CR[1], CR[1]));
    PH = PH + pkfma(CI[3], CI[3], pkmul(CR[3], CR[3]));
    v2f X = pkfma(CI[0], CI[1], pkmul(CR[0], CR[1]));
    X = X + pkfma(CI[2], CI[3], pkmul(CR[2], CR[3]));
    v2f Y = pkmul(CR[0], CI[1]) - pkmul(CI[0], CR[1]);
    Y = Y + (pkmul(CR[2], CI[3]) - pkmul(CI[2], CR[3]));
    v2f EV = pkfma(dup(wb), Y, pkfma(dup(wa), X,
             pkfma(dup(w11), PH, pkmul(dup(w00), PL))));
    float v = EV.x + EV.y;
    v += shxm<1>(v); v += shxm<2>(v); v += shxm<4>(v);
    v += shxm<8>(v); v += shxm<16>(v);
    if (l == 0) out[b] = fmaxf(v, 0.f);
  }
}

extern "C" void kernel_launch(void* const* d_in, const int* in_sizes, int n_in,
                              void* d_out, int out_size, void* d_ws, size_t ws_size,
                              hipStream_t stream) {
  const float* theta = (const float*)d_in[0];
  const float* phi = (const float*)d_in[1];
  const float* crx = (const float*)d_in[2];
  const float* u3p = (const float*)d_in[3];
  float* out = (float*)d_out;
  float* ws = (float*)d_ws;
  const int nb = in_sizes[0];

  prep_kernel<<<1, 64, 0, stream>>>(crx, u3p, ws);

  const int elems_per_block = 8;  // 4 waves * 2 elements
  dim3 block(256);
  dim3 grid((nb + elems_per_block - 1) / elems_per_block);
  qcnn_kernel<<<grid, block, 0, stream>>>(theta, phi, ws, out, nb);
}